// Round 6
// baseline (166.784 us; speedup 1.0000x reference)
//
#include <hip/hip_runtime.h>

#define IN_F 4096
#define OUT_F 16384
#define M_ROWS 512

#define BM 512
#define BN 128
#define BK 32
#define KSPAN 2048
#define NKT (KSPAN / BK)   // 64
#define THREADS 1024

typedef __bf16 bf16x8_t __attribute__((ext_vector_type(8)));
typedef float f32x4_t __attribute__((ext_vector_type(4)));
typedef int i32x4_t __attribute__((ext_vector_type(4)));

__device__ __forceinline__ void gld16(const void* g, void* l) {
    __builtin_amdgcn_global_load_lds(
        (const __attribute__((address_space(1))) void*)g,
        (__attribute__((address_space(3))) void*)l,
        16 /*bytes, literal*/, 0, 0);
}

// ---------------- pre-pass 1: x fp32 -> bf16 tiles [128 g_kt][512 r][32 c], plain ----------------
__global__ __launch_bounds__(256)
void xpack_kernel(const float* __restrict__ x, __bf16* __restrict__ xp) {
    const int tid = blockIdx.x * 256 + (int)threadIdx.x;  // 262144 threads
    const int e0 = tid * 8;
    const int g_kt = e0 >> 14;          // 16384 elems (32 KB) per tile
    const int rem = e0 & 16383;
    const int r = rem >> 5;             // 0..511
    const int c0 = rem & 31;            // {0,8,16,24}
    const float* src = x + (size_t)r * IN_F + g_kt * 32 + c0;
    f32x4_t a = *(const f32x4_t*)(src);
    f32x4_t b = *(const f32x4_t*)(src + 4);
    bf16x8_t o;
    o[0] = (__bf16)a[0]; o[1] = (__bf16)a[1]; o[2] = (__bf16)a[2]; o[3] = (__bf16)a[3];
    o[4] = (__bf16)b[0]; o[5] = (__bf16)b[1]; o[6] = (__bf16)b[2]; o[7] = (__bf16)b[3];
    *(bf16x8_t*)(xp + e0) = o;
}

// ---------------- pre-pass 2: out[r][c] = bias[c] (atomic accumulation target) ----------------
__global__ __launch_bounds__(256)
void bias_init_kernel(const float* __restrict__ bias, float* __restrict__ out) {
    const int idx = blockIdx.x * 256 + (int)threadIdx.x;   // 2M f32x4 stores
    const int c4 = idx & 4095;                             // 4096 f32x4 per row
    f32x4_t b = *(const f32x4_t*)(bias + c4 * 4);
    *(f32x4_t*)(out + (size_t)idx * 4) = b;
}

// ---------------- main GEMM: split-K, exclusive Wq read, L2-resident x-half ----------------
// grid 256 = 2 kh x 128 nt (XCD-grouped: one kh per XCD -> 2MB xp footprint in L2).
// 1024 thr = 16 waves (4M x 4N), wave-tile 128x32, acc 64 VGPR. LDS 96 KB, 1 blk/CU, 4 waves/SIMD.
__global__ __launch_bounds__(THREADS, 4)
void qgemm6_kernel(const __bf16* __restrict__ xp, const int* __restrict__ Wq,
                   const float* __restrict__ scales, float* __restrict__ out) {
    __shared__ __align__(16) unsigned char sA[2][BM * BK * 2];   // 2 x 32 KB bf16, linear
    __shared__ __align__(16) unsigned char sB[2][BN * BK * 4];   // 2 x 16 KB int32, chunk-XOR

    const int bid = (int)blockIdx.x;
    const int xcd = bid & 7;
    const int slot = bid >> 3;                 // 0..31
    const int kh = xcd >> 2;                   // XCDs 0-3 -> kh0, 4-7 -> kh1
    const int nt = (xcd & 3) * 32 + slot;      // 0..127
    const int bcol = nt * BN;
    const int kbase = kh * KSPAN;              // int32-element offset in Wq rows
    const int gkt0 = kh * NKT;                 // xp tile base

    const int t = (int)threadIdx.x;
    const int lane = t & 63;
    const int wid = t >> 6;                    // 16 waves
    const int wm = wid >> 2;                   // 0..3  (128-row stripe)
    const int wn = wid & 3;                    // 0..3  (32-col stripe)

    // ---- A-DMA: 32 KB/kt = 2 ops/thread; xp tile layout == LDS layout (linear) ----
    const __bf16* xt = xp + (size_t)gkt0 * (BM * BK);   // + kt*16384 elems
    const int ldsA0 = wid * 1024;                        // wave-uniform; HW adds lane*16

    // ---- B-DMA: 16 KB/kt = 1 op/thread; pre-swizzled global chunk ----
    const int rb = t >> 3;                     // 0..127 (Wq row within panel)
    const int cch = (t & 7) ^ (rb & 7);        // fetched 16B chunk (inverse swizzle)
    const int* wg = Wq + (size_t)(bcol + rb) * IN_F + kbase + cch * 4;
    const int ldsB0 = wid * 1024;              // wave-uniform; lane*16 = rb*128 + (t&7)*16

#define ISSUE_TILE(KT_, PB_)                                            \
    do {                                                                \
        const __bf16* sa_ = xt + (size_t)(KT_) * (BM * BK);             \
        unsigned char* da_ = &sA[PB_][0] + ldsA0;                       \
        gld16(sa_ + (size_t)t * 8, da_);                                \
        gld16(sa_ + (size_t)t * 8 + 8192, da_ + 16384);                 \
        gld16(wg + (size_t)(KT_) * BK, &sB[PB_][0] + ldsB0);            \
    } while (0)

    f32x4_t acc[8][2];
#pragma unroll
    for (int m = 0; m < 8; ++m)
#pragma unroll
        for (int n = 0; n < 2; ++n) {
            f32x4_t z = {0.f, 0.f, 0.f, 0.f};
            acc[m][n] = z;
        }

    const int arow = wm * 128 + (lane & 15);   // + m*16
    const int g = lane >> 4;                   // k-chunk 0..3
    const int brow0 = wn * 32 + (lane & 15);   // + n*16

    // -------- prologue: tile 0 into LDS[0] (r5 bug: this was missing) --------
    ISSUE_TILE(0, 0);

#pragma unroll 1
    for (int kt = 0; kt < NKT; ++kt) {
        const int cur = kt & 1;
        __syncthreads();   // waitcnt vmcnt(0) lgkmcnt(0) + barrier: DMA(kt) now in LDS[cur]

        // ---- prefetch kt+1 into LDS[cur^1] (that buffer's readers finished pre-barrier) ----
        {
            const int kn = (kt + 1 < NKT) ? kt + 1 : NKT - 1;
            ISSUE_TILE(kn, cur ^ 1);
        }

        // ---- B fragments: int32 from LDS, cvt to bf16 ----
        bf16x8_t bfc[2];
#pragma unroll
        for (int n = 0; n < 2; ++n) {
            const int r_ = brow0 + n * 16;
            const int x_ = r_ & 7;
            const unsigned char* pb = &sB[cur][0] + r_ * 128;
            i32x4_t lo = *(const i32x4_t*)(pb + (((g * 2 + 0) ^ x_) << 4));
            i32x4_t hi = *(const i32x4_t*)(pb + (((g * 2 + 1) ^ x_) << 4));
#pragma unroll
            for (int j = 0; j < 4; ++j) {
                bfc[n][j] = (__bf16)(float)lo[j];
                bfc[n][4 + j] = (__bf16)(float)hi[j];
            }
        }

        // ---- A fragments + MFMA, m in two halves (VGPR control) ----
#pragma unroll
        for (int mh = 0; mh < 2; ++mh) {
            bf16x8_t af[4];
#pragma unroll
            for (int m = 0; m < 4; ++m) {
                const int r_ = arow + (mh * 4 + m) * 16;
                af[m] = *(const bf16x8_t*)(&sA[cur][0] + r_ * 64 + g * 16);
            }
#pragma unroll
            for (int m = 0; m < 4; ++m)
#pragma unroll
                for (int n = 0; n < 2; ++n)
                    acc[mh * 4 + m][n] = __builtin_amdgcn_mfma_f32_16x16x32_bf16(
                        af[m], bfc[n], acc[mh * 4 + m][n], 0, 0, 0);
        }
    }
#undef ISSUE_TILE

    // ---- epilogue: scale + atomic accumulate into bias-initialized out ----
    // C/D layout: col = lane&15, row = (lane>>4)*4 + reg (m89-verified, r1-r4-validated)
    const int orow0 = wm * 128 + ((lane >> 4) << 2);
    const int ocol0 = bcol + wn * 32 + (lane & 15);
#pragma unroll
    for (int n = 0; n < 2; ++n) {
        const int c = ocol0 + n * 16;
        const float sc = scales[c];
#pragma unroll
        for (int m = 0; m < 8; ++m) {
            const int r = orow0 + m * 16;
            float* po = out + (size_t)r * OUT_F + c;
#pragma unroll
            for (int j = 0; j < 4; ++j) {
                __hip_atomic_fetch_add(po + (size_t)j * OUT_F, acc[m][n][j] * sc,
                                       __ATOMIC_RELAXED, __HIP_MEMORY_SCOPE_AGENT);
            }
        }
    }
}

// ---------------- fallback (no workspace): round-1 kernel, known-correct ----------------
__global__ __launch_bounds__(256, 2)
void qgemm_fallback(const float* __restrict__ x, const int* __restrict__ Wq,
                    const float* __restrict__ scales, const float* __restrict__ bias,
                    float* __restrict__ out) {
    __shared__ __align__(16) unsigned char fA[128 * 64 * 2];
    __shared__ __align__(16) unsigned char fB[128 * 64 * 2];

    const int bid = (int)blockIdx.x;
    const int gsw = (bid & 7) * 64 + (bid >> 3);
    const int mt = gsw & 3;
    const int ntf = gsw >> 2;
    const int brow = mt * 128;
    const int bcolf = ntf * 128;

    const int t = (int)threadIdx.x;
    const int lane = t & 63;
    const int wid = t >> 6;
    const int wr = wid >> 1;
    const int wc = wid & 1;

    const int srow = t >> 4;
    const int sc4 = t & 15;

    const float* xg = x + (size_t)(brow + srow) * IN_F + sc4 * 4;
    const int* wgf = Wq + (size_t)(bcolf + srow) * IN_F + sc4 * 4;

    f32x4_t acc[4][4];
#pragma unroll
    for (int i = 0; i < 4; ++i)
#pragma unroll
        for (int j = 0; j < 4; ++j) {
            f32x4_t z = {0.f, 0.f, 0.f, 0.f};
            acc[i][j] = z;
        }

    const int frow_a = wr * 64 + (lane & 15);
    const int frow_b = wc * 64 + (lane & 15);
    const int fk = (lane >> 4) * 16;

#pragma unroll 1
    for (int kt = 0; kt < IN_F / 64; ++kt) {
        const int k0 = kt * 64;
        f32x4_t av[8];
        i32x4_t bv[8];
#pragma unroll
        for (int i = 0; i < 8; ++i) {
            av[i] = *(const f32x4_t*)(xg + k0 + (size_t)i * 16 * IN_F);
            bv[i] = *(const i32x4_t*)(wgf + k0 + (size_t)i * 16 * IN_F);
        }
        __syncthreads();
#pragma unroll
        for (int i = 0; i < 8; ++i) {
            const int row = srow + i * 16;
            unsigned off = (unsigned)(row * 128 + sc4 * 8);
            off ^= (unsigned)(row & 7) << 4;
            __bf16 pa[4], pb[4];
#pragma unroll
            for (int j = 0; j < 4; ++j) {
                pa[j] = (__bf16)av[i][j];
                pb[j] = (__bf16)(float)bv[i][j];
            }
            *(unsigned long long*)(fA + off) = *(unsigned long long*)pa;
            *(unsigned long long*)(fB + off) = *(unsigned long long*)pb;
        }
        __syncthreads();
#pragma unroll
        for (int ks = 0; ks < 2; ++ks) {
            bf16x8_t afv[4], bfv[4];
#pragma unroll
            for (int m = 0; m < 4; ++m) {
                const int row = frow_a + m * 16;
                afv[m] = *(const bf16x8_t*)(fA + (row * 128 + ((ks * 64 + fk) ^ ((row & 7) << 4))));
            }
#pragma unroll
            for (int n = 0; n < 4; ++n) {
                const int row = frow_b + n * 16;
                bfv[n] = *(const bf16x8_t*)(fB + (row * 128 + ((ks * 64 + fk) ^ ((row & 7) << 4))));
            }
#pragma unroll
            for (int m = 0; m < 4; ++m)
#pragma unroll
                for (int n = 0; n < 4; ++n)
                    acc[m][n] = __builtin_amdgcn_mfma_f32_16x16x32_bf16(
                        afv[m], bfv[n], acc[m][n], 0, 0, 0);
        }
    }

    const int orow = brow + wr * 64 + ((lane >> 4) << 2);
    const int ocol = bcolf + wc * 64 + (lane & 15);
#pragma unroll
    for (int n = 0; n < 4; ++n) {
        const int c = ocol + n * 16;
        const float sc = scales[c];
        const float bs = bias[c];
#pragma unroll
        for (int m = 0; m < 4; ++m) {
            const int r = orow + m * 16;
            float* po = out + (size_t)r * OUT_F + c;
#pragma unroll
            for (int j = 0; j < 4; ++j) {
                po[(size_t)j * OUT_F] = acc[m][n][j] * sc + bs;
            }
        }
    }
}

extern "C" void kernel_launch(void* const* d_in, const int* in_sizes, int n_in,
                              void* d_out, int out_size, void* d_ws, size_t ws_size,
                              hipStream_t stream) {
    const float* x = (const float*)d_in[0];
    const int* Wq = (const int*)d_in[1];
    const float* scales = (const float*)d_in[2];
    const float* bias = (const float*)d_in[3];
    float* out = (float*)d_out;

    const size_t xp_bytes = (size_t)M_ROWS * IN_F * 2;  // 4 MB
    const bool pre = (ws_size >= xp_bytes) && (d_ws != nullptr);

    if (pre) {
        __bf16* xp = (__bf16*)d_ws;
        xpack_kernel<<<dim3((M_ROWS * IN_F / 8) / 256), dim3(256), 0, stream>>>(x, xp);
        bias_init_kernel<<<dim3((M_ROWS * OUT_F / 4) / 256), dim3(256), 0, stream>>>(bias, out);
        qgemm6_kernel<<<dim3(256), dim3(THREADS), 0, stream>>>(xp, Wq, scales, out);
    } else {
        qgemm_fallback<<<dim3(512), dim3(256), 0, stream>>>(x, Wq, scales, bias, out);
    }
}